// Round 8
// baseline (30787.891 us; speedup 1.0000x reference)
//
#include <hip/hip_runtime.h>
#include <math.h>

// dQPEq: primal-dual IPM for  min 0.5*mu*||z||^2 + q^T z  s.t. Az=b, z>=0
// mu=0.1, sigma=0.1. fp64 state/residuals, fp32 A/Schur/Cholesky. NITER=14.
// R8: de-spill k_panel. R7's fused panel hit VGPR=256 + scratch spills
// (constant 388us dispatches, VALUBusy 0.036%, FETCH ~ spill bytes).
// Triangular solves now LDS-resident with NON-unrolled dynamic loops:
// no 64-float register arrays, no giant unrolled code. Launch structure
// unchanged (15/iter, math bit-validated vs R6 at absmax 0.03125).

#define NX 4096
#define NEQ 768
#define MUQ 0.1
#define SIGC 0.1
#define NITER 14

__device__ inline double blockReduceSum(double v, double* red){
  int t = threadIdx.x;
  red[t] = v; __syncthreads();
  for (int s = 128; s > 0; s >>= 1){
    if (t < s) red[t] += red[t + s];
    __syncthreads();
  }
  return red[0];
}
__device__ inline double blockReduceMin(double v, double* red){
  int t = threadIdx.x;
  red[t] = v; __syncthreads();
  for (int s = 128; s > 0; s >>= 1){
    if (t < s) red[t] = fmin(red[t], red[t + s]);
    __syncthreads();
  }
  return red[0];
}

// ---------------- dtype detection (R4-proven) ----------------
__global__ void k_detect(const float* __restrict__ Af, int* __restrict__ flag){
  __shared__ int bad;
  if (threadIdx.x == 0) bad = 0;
  __syncthreads();
  for (int i = threadIdx.x; i < 2048; i += 256){
    float f = Af[i];
    if (!(f >= 0.0f && f < 1.0f)) bad = 1;
  }
  __syncthreads();
  if (threadIdx.x == 0) *flag = bad;         // 1 => buffer is fp64
}

__global__ void k_convert(const void* __restrict__ Aptr, const int* __restrict__ flag,
                          float* __restrict__ A32){
  int idx = blockIdx.x * 256 + threadIdx.x;
  if (*flag){
    const double* Ad = (const double*)Aptr;
    for (int s = 0; s < 4; ++s){ int e = idx + s * 786432; A32[e] = (float)Ad[e]; }
  } else {
    const float* Afl = (const float*)Aptr;
    for (int s = 0; s < 4; ++s){ int e = idx + s * 786432; A32[e] = Afl[e]; }
  }
}

// ---------------- setup ----------------
__global__ void k_setup(const float* __restrict__ puz, const void* __restrict__ lz0p,
                        const int* __restrict__ flag,
                        double* q, double* ez, double* z, double* lam, double* nu,
                        unsigned int* cnts){
  int b = blockIdx.x, t = threadIdx.x;
  if (b < 16){
    int k = b * 256 + t;
    q[k] = -(double)puz[k];
    double lv = (*flag) ? ((const double*)lz0p)[k] : (double)((const float*)lz0p)[k];
    ez[k] = exp(lv);
    z[k] = 1.0; lam[k] = 1.0;
  } else {
    for (int i = t; i < NEQ; i += 256) nu[i] = 0.0;
    if (t < 2) cnts[t] = 0;
  }
}

__global__ void k_bvec(const float* __restrict__ A32, const double* __restrict__ ez,
                       double* __restrict__ bv){
  __shared__ double red[256];
  int i = blockIdx.x, t = threadIdx.x;
  const float* Ar = A32 + (size_t)i * NX;
  double acc = 0.0;
  for (int s = 0; s < 16; ++s){ int k = t + s * 256; acc += (double)Ar[k] * ez[k]; }
  acc = blockReduceSum(acc, red);
  if (t == 0) bv[i] = acc;
}

// ---------------- fused residuals + elementwise prep + ADA zeroing ----------
__global__ __launch_bounds__(256) void k_resid_elem(
    const float* __restrict__ A32, const double* __restrict__ nu,
    const double* __restrict__ z, const double* __restrict__ lam,
    const double* __restrict__ bv, const double* __restrict__ q,
    double* __restrict__ atnu_part, double* __restrict__ rp,
    double* __restrict__ gap_slot,
    double* __restrict__ rtil, double* __restrict__ rc,
    double* __restrict__ Di64, float* __restrict__ Di32,
    float* __restrict__ w32, float* __restrict__ ADA,
    unsigned int* __restrict__ cnt){
  __shared__ double red[256];
  __shared__ unsigned int ticket;
  int b = blockIdx.x, t = threadIdx.x;
  if (b < 576){
    size_t idx = ((size_t)b * 256 + t) * 4;
    float4 zf; zf.x = 0.f; zf.y = 0.f; zf.z = 0.f; zf.w = 0.f;
    *(float4*)(ADA + idx) = zf;                 // 576*1024 = 589824 floats
  }
  if (b < 64){
    int kblk = b & 15, ch = b >> 4;
    int k = kblk * 256 + t;
    double acc = 0.0;
    int i0 = ch * 192;
    for (int i = i0; i < i0 + 192; ++i) acc += (double)A32[(size_t)i * NX + k] * nu[i];
    atnu_part[ch * NX + k] = acc;
  } else if (b < 832){
    int i = b - 64;
    const float* Ar = A32 + (size_t)i * NX;
    double acc = 0.0;
    for (int s = 0; s < 16; ++s){ int k = t + s * 256; acc += (double)Ar[k] * z[k]; }
    acc = blockReduceSum(acc, red);
    if (t == 0) rp[i] = acc - bv[i];
  } else {
    double acc = 0.0;
    for (int s = 0; s < 16; ++s){ int k = t + s * 256; acc += z[k] * lam[k]; }
    acc = blockReduceSum(acc, red);
    if (t == 0) *gap_slot = acc;
  }
  __threadfence();
  __syncthreads();
  if (t == 0) ticket = atomicAdd(cnt, 1u);
  __syncthreads();
  if (ticket != 832u) return;
  __threadfence();
  double gap = (*gap_slot) * (1.0 / NX);
  for (int k = t; k < NX; k += 256){
    double atnu = atnu_part[k] + atnu_part[NX + k]
                + atnu_part[2*NX + k] + atnu_part[3*NX + k];
    double zk = z[k], lk = lam[k];
    double rd  = MUQ * zk + q[k] - lk + atnu;
    double rcv = zk * lk - SIGC * gap;
    double di  = 1.0 / (MUQ + lk / zk);
    double rt  = -rd - rcv / zk;
    rtil[k] = rt; rc[k] = rcv; Di64[k] = di;
    Di32[k] = (float)di;
    w32[k]  = (float)(rt * di);
  }
  if (t == 0) *cnt = 0u;
}

// blocks 0..155: lower tiles (78 pairs x ksplit2), 2-way atomicAdd (order-invariant)
// blocks 156..923: rhs rows: rhs = A@w + rp   (R5/R6/R7-proven)
__global__ __launch_bounds__(256) void k_ada(const float* __restrict__ A32,
                      const float* __restrict__ Di32, const float* __restrict__ w32,
                      const double* __restrict__ rp,
                      float* __restrict__ ADA, float* __restrict__ rhs){
  __shared__ float As[16][68], Bs[16][68];
  __shared__ double red[256];
  int b = blockIdx.x, tid = threadIdx.x;
  if (b < 156){
    int pr = b >> 1, ks = b & 1;
    int ti = 0;
    while ((ti + 1) * (ti + 2) / 2 <= pr) ++ti;
    int tj = pr - ti * (ti + 1) / 2;
    int lr = tid >> 2, lq = tid & 3;
    int tx = tid & 15, ty = tid >> 4;
    const float* Arow = A32 + (size_t)(ti * 64 + lr) * NX;
    const float* Brow = A32 + (size_t)(tj * 64 + lr) * NX;
    float c44[4][4];
#pragma unroll
    for (int i = 0; i < 4; ++i)
#pragma unroll
      for (int j = 0; j < 4; ++j) c44[i][j] = 0.0f;
    int k0 = ks * 2048;
    for (int kk = k0; kk < k0 + 2048; kk += 16){
#pragma unroll
      for (int s = 0; s < 4; ++s){
        int kc = kk + lq * 4 + s;
        As[lq * 4 + s][lr] = Arow[kc];
        Bs[lq * 4 + s][lr] = Brow[kc] * Di32[kc];
      }
      __syncthreads();
#pragma unroll
      for (int m = 0; m < 16; ++m){
        float4 aa = *(const float4*)&As[m][ty * 4];
        float4 bb = *(const float4*)&Bs[m][tx * 4];
        float a4[4] = {aa.x, aa.y, aa.z, aa.w};
        float b4[4] = {bb.x, bb.y, bb.z, bb.w};
#pragma unroll
        for (int i = 0; i < 4; ++i)
#pragma unroll
          for (int j = 0; j < 4; ++j) c44[i][j] += a4[i] * b4[j];
      }
      __syncthreads();
    }
#pragma unroll
    for (int i = 0; i < 4; ++i){
      int row = ti * 64 + ty * 4 + i;
#pragma unroll
      for (int j = 0; j < 4; ++j){
        int col = tj * 64 + tx * 4 + j;
        atomicAdd(&ADA[(size_t)row * 768 + col], c44[i][j]);
      }
    }
  } else {
    int r = b - 156;
    const float* Ar = A32 + (size_t)r * NX;
    double acc = 0.0;
    for (int s = 0; s < 16; ++s){
      int k = tid + s * 256;
      acc += (double)Ar[k] * (double)w32[k];
    }
    acc = blockReduceSum(acc, red);
    if (tid == 0) rhs[r] = (float)(acc + rp[r]);
  }
}

// ---------------- left-looking fused panel kernel (LDS solves, no spills) ---
// Launch p = 0..11 with grid (12-p). Block g handles row-tile r = p+g:
//   U  = ADAraw[r,p] - L[r,0:K] @ L[p,0:K]^T        (K = 64p)
//   Ud = ADAraw[p,p] - L[p,0:K] @ L[p,0:K]^T        (redundant per block)
//   chol(Ud) in LDS (dynamic loops); g==0 also fwd-elims rhs -> y_p.
//   g>0: trsm in LDS  L[r,p] = U * L_pp^{-T}.
//   p==11 (single block): fused LDS backsolve L^T dnu = y.
__global__ __launch_bounds__(256) void k_panel(float* __restrict__ ADA,
                                               float* __restrict__ rhs,
                                               float* __restrict__ dnu32, int p){
  int g = blockIdx.x;
  int r = p + g;
  int tid = threadIdx.x;
  int tx = tid & 15, ty = tid >> 4;
  int lr = tid >> 2, lq = tid & 3;
  __shared__ float As[16][68], Bs[16][68];
  __shared__ float Cs[64][65], Us[64][65];   // stride 65: conflict-free rows
  __shared__ float colj[64], rvs[64], xsh[64], ysh[16];
  float c1[4][4], c2[4][4];
#pragma unroll
  for (int i = 0; i < 4; ++i)
#pragma unroll
    for (int j = 0; j < 4; ++j){ c1[i][j] = 0.0f; c2[i][j] = 0.0f; }
  float racc = 0.0f;
  const int K = p * 64;

  // -------- GEMM phase (R7-proven structure) --------
  for (int k0 = 0; k0 < K; k0 += 16){
#pragma unroll
    for (int s = 0; s < 4; ++s){
      int kc = k0 + lq * 4 + s;
      As[lq * 4 + s][lr] = ADA[(size_t)(r * 64 + lr) * 768 + kc];
      Bs[lq * 4 + s][lr] = ADA[(size_t)(p * 64 + lr) * 768 + kc];
    }
    if (tid < 16) ysh[tid] = rhs[k0 + tid];
    __syncthreads();
#pragma unroll
    for (int m = 0; m < 16; ++m){
      float4 aa = *(const float4*)&As[m][ty * 4];
      float4 ab = *(const float4*)&Bs[m][ty * 4];
      float4 bb = *(const float4*)&Bs[m][tx * 4];
      float a1[4] = {aa.x, aa.y, aa.z, aa.w};
      float a2[4] = {ab.x, ab.y, ab.z, ab.w};
      float b4[4] = {bb.x, bb.y, bb.z, bb.w};
#pragma unroll
      for (int i = 0; i < 4; ++i)
#pragma unroll
        for (int j = 0; j < 4; ++j){
          c1[i][j] += a1[i] * b4[j];
          c2[i][j] += a2[i] * b4[j];
        }
    }
    if (tid < 64){
      float rsum = 0.0f;
#pragma unroll
      for (int m = 0; m < 16; ++m) rsum += Bs[m][tid] * ysh[m];
      racc += rsum;
    }
    __syncthreads();
  }

  // -------- finalize: Us = raw[r,p] - c1 ; Cs = raw[p,p] - c2 --------
#pragma unroll
  for (int i = 0; i < 4; ++i){
    float4 v1 = *(const float4*)&ADA[(size_t)(r * 64 + ty * 4 + i) * 768 + p * 64 + tx * 4];
    float4 v2 = *(const float4*)&ADA[(size_t)(p * 64 + ty * 4 + i) * 768 + p * 64 + tx * 4];
    Us[ty * 4 + i][tx * 4 + 0] = v1.x - c1[i][0];
    Us[ty * 4 + i][tx * 4 + 1] = v1.y - c1[i][1];
    Us[ty * 4 + i][tx * 4 + 2] = v1.z - c1[i][2];
    Us[ty * 4 + i][tx * 4 + 3] = v1.w - c1[i][3];
    Cs[ty * 4 + i][tx * 4 + 0] = v2.x - c2[i][0];
    Cs[ty * 4 + i][tx * 4 + 1] = v2.y - c2[i][1];
    Cs[ty * 4 + i][tx * 4 + 2] = v2.z - c2[i][2];
    Cs[ty * 4 + i][tx * 4 + 3] = v2.w - c2[i][3];
  }
  if (tid < 64) rvs[tid] = rhs[p * 64 + tid] - racc;
  __syncthreads();

  // -------- LDS Cholesky of Cs + rhs forward elimination --------
  // pre-scale form (R4-proven algebra): ar = M[r][j]/v ; L[r][j] = ar*d ;
  // rv_r -= ar * rvj ; y_j = rvj/d.  Trailing cols split over 4 waves.
  {
    int rr = tid & 63, w = tid >> 6;
#pragma unroll 1
    for (int j = 0; j < 64; ++j){
      if (tid < 64) colj[tid] = Cs[tid][j];
      __syncthreads();
      float v = fmaxf(colj[j], 1e-12f);
      float invv = 1.0f / v;
      float d = sqrtf(v);
      float rvj = rvs[j];
      __syncthreads();
      if (rr > j){
        float ar = colj[rr] * invv;
#pragma unroll 1
        for (int c = j + 1 + w; c <= rr; c += 4)
          Cs[rr][c] -= ar * colj[c];
        if (w == 0){
          rvs[rr] -= ar * rvj;
          Cs[rr][j] = ar * d;
        }
      } else if (rr == j && w == 0){
        Cs[j][j] = d;
        rvs[j] = rvj / d;
      }
      __syncthreads();
    }
  }

  if (g == 0){
    if (tid < 64) rhs[p * 64 + tid] = rvs[tid];     // y_p
    for (int idx = tid; idx < 4096; idx += 256){
      int row = idx >> 6, c = idx & 63;
      if (c <= row) ADA[(size_t)(p * 64 + row) * 768 + p * 64 + c] = Cs[row][c];
    }
  } else {
    // -------- LDS trsm: rows independent, thread t = row, no barriers ------
    if (tid < 64){
#pragma unroll 1
      for (int j = 0; j < 64; ++j){
        float xj = Us[tid][j] / Cs[j][j];
        Us[tid][j] = xj;
#pragma unroll 1
        for (int c = j + 1; c < 64; ++c)
          Us[tid][c] -= xj * Cs[c][j];
      }
    }
    __syncthreads();
    for (int idx = tid; idx < 4096; idx += 256){
      int row = idx >> 6, c = idx & 63;
      ADA[(size_t)(r * 64 + row) * 768 + p * 64 + c] = Us[row][c];
    }
  }

  // -------- fused backward solve (panel 11 only; grid==1 block) --------
  if (p == 11){
    __syncthreads();
#pragma unroll 1
    for (int bb = 11; bb >= 0; --bb){
      int base = bb * 64;
      if (bb != 11){
        for (int idx = tid; idx < 4096; idx += 256){
          int row = idx >> 6, c = idx & 63;
          Cs[row][c] = ADA[(size_t)(base + row) * 768 + base + c];
        }
        if (tid < 64) rvs[tid] = rhs[base + tid];
        __syncthreads();
      }
      // sequential L^T x = y over this 64-block
#pragma unroll 1
      for (int j = 63; j >= 0; --j){
        float xj = rvs[j] / Cs[j][j];
        if (tid == (unsigned)j){ dnu32[base + j] = xj; xsh[j] = xj; }
        if (tid < (unsigned)j) rvs[tid] -= Cs[j][tid] * xj;
        __syncthreads();
      }
      // rhs_above -= L(bb,0:base)^T x
      for (int r2 = tid; r2 < base; r2 += 256){
        float acc = 0.0f;
#pragma unroll 1
        for (int k = 0; k < 64; ++k)
          acc += ADA[(size_t)(base + k) * 768 + r2] * xsh[k];
        rhs[r2] -= acc;
      }
      __syncthreads();
    }
  }
}

// ---------------- fused A^T dnu + step + update (last-block ticket) --------
__global__ __launch_bounds__(256) void k_atd_step(
    const float* __restrict__ A32, const float* __restrict__ dnu32,
    float* __restrict__ atd_part,
    const double* __restrict__ rtil, const double* __restrict__ rc,
    const double* __restrict__ Di64,
    double* __restrict__ z, double* __restrict__ lam, double* __restrict__ nu,
    unsigned int* __restrict__ cnt){
  __shared__ double red[256];
  __shared__ unsigned int ticket;
  int bx = blockIdx.x, t = threadIdx.x;
  int kblk = bx & 15, ch = bx >> 4;
  int k = kblk * 256 + t;
  double acc = 0.0;
  int i0 = ch * 192;
  for (int i = i0; i < i0 + 192; ++i)
    acc += (double)A32[(size_t)i * NX + k] * (double)dnu32[i];
  atd_part[ch * NX + k] = (float)acc;
  __threadfence();
  __syncthreads();
  if (t == 0) ticket = atomicAdd(cnt, 1u);
  __syncthreads();
  if (ticket != 63u) return;
  __threadfence();
  double dzl[16], dll[16];
  double amin = INFINITY;
#pragma unroll
  for (int s = 0; s < 16; ++s){
    int kk = t + s * 256;
    double atd = (double)atd_part[kk] + (double)atd_part[NX + kk]
               + (double)atd_part[2*NX + kk] + (double)atd_part[3*NX + kk];
    double dzk = (rtil[kk] - atd) * Di64[kk];
    double zk = z[kk], lk = lam[kk];
    double dlk = (-rc[kk] - lk * dzk) / zk;
    dzl[s] = dzk; dll[s] = dlk;
    if (dzk < 0.0) amin = fmin(amin, -zk / dzk);
    if (dlk < 0.0) amin = fmin(amin, -lk / dlk);
  }
  amin = blockReduceMin(amin, red);
  double alpha = fmin(1.0, 0.99 * amin);
#pragma unroll
  for (int s = 0; s < 16; ++s){
    int kk = t + s * 256;
    z[kk]   += alpha * dzl[s];
    lam[kk] += alpha * dll[s];
  }
  for (int i = t; i < NEQ; i += 256) nu[i] += alpha * (double)dnu32[i];
  if (t == 0) *cnt = 0u;
}

__global__ void k_out(const double* __restrict__ z, float* __restrict__ out){
  int k = blockIdx.x * 256 + threadIdx.x;
  out[k] = (float)z[k];
}

// ---------------- host ----------------
extern "C" void kernel_launch(void* const* d_in, const int* in_sizes, int n_in,
                              void* d_out, int out_size, void* d_ws, size_t ws_size,
                              hipStream_t stream){
  const float* puz  = (const float*)d_in[0];
  const void*  Ap   = d_in[1];
  const void*  lz0p = d_in[2];
  float* out = (float*)d_out;
  char* w = (char*)d_ws;

  size_t o = 0;
  float* A32 = (float*)(w + o);        o += (size_t)NEQ * NX * 4;     // 12.58 MB
  float* ADA = (float*)(w + o);        o += (size_t)768 * 768 * 4;    // 2.36 MB
  double* q    = (double*)(w + o);     o += NX * 8;
  double* ez   = (double*)(w + o);     o += NX * 8;
  double* z    = (double*)(w + o);     o += NX * 8;
  double* lam  = (double*)(w + o);     o += NX * 8;
  double* rtil = (double*)(w + o);     o += NX * 8;
  double* rc   = (double*)(w + o);     o += NX * 8;
  double* Di64 = (double*)(w + o);     o += NX * 8;
  double* atnu = (double*)(w + o);     o += 4ull * NX * 8;
  double* nu   = (double*)(w + o);     o += NEQ * 8;
  double* bv   = (double*)(w + o);     o += NEQ * 8;
  double* rp   = (double*)(w + o);     o += NEQ * 8;
  double* gap_slot = (double*)(w + o); o += 8;
  float* Di32  = (float*)(w + o);      o += NX * 4;
  float* w32   = (float*)(w + o);      o += NX * 4;
  float* atd_part = (float*)(w + o);   o += 4ull * NX * 4;
  float* rhs   = (float*)(w + o);      o += NEQ * 4;
  float* dnu32 = (float*)(w + o);      o += NEQ * 4;
  int*   dflag = (int*)(w + o);        o += 16;
  unsigned int* cnts = (unsigned int*)(w + o); o += 16;
  (void)ws_size; (void)in_sizes; (void)n_in; (void)out_size;   // ~15.5 MB used

  k_detect<<<1, 256, 0, stream>>>((const float*)Ap, dflag);
  k_convert<<<3072, 256, 0, stream>>>(Ap, dflag, A32);
  k_setup<<<17, 256, 0, stream>>>(puz, lz0p, dflag, q, ez, z, lam, nu, cnts);
  k_bvec<<<768, 256, 0, stream>>>(A32, ez, bv);

  for (int it = 0; it < NITER; ++it){
    k_resid_elem<<<833, 256, 0, stream>>>(A32, nu, z, lam, bv, q,
                                          atnu, rp, gap_slot,
                                          rtil, rc, Di64, Di32, w32, ADA, cnts);
    k_ada<<<924, 256, 0, stream>>>(A32, Di32, w32, rp, ADA, rhs);
    for (int p = 0; p < 12; ++p)
      k_panel<<<12 - p, 256, 0, stream>>>(ADA, rhs, dnu32, p);
    k_atd_step<<<64, 256, 0, stream>>>(A32, dnu32, atd_part,
                                       rtil, rc, Di64, z, lam, nu, cnts + 1);
  }
  k_out<<<16, 256, 0, stream>>>(z, out);
}

// Round 9
// 19145.871 us; speedup vs baseline: 1.6081x; 1.6081x over previous
//
#include <hip/hip_runtime.h>
#include <math.h>

// dQPEq: primal-dual IPM for  min 0.5*mu*||z||^2 + q^T z  s.t. Az=b, z>=0
// mu=0.1, sigma=0.1. fp64 state/residuals, fp32 A/Schur/Cholesky. NITER=14.
// R9: R6's proven chain with launch-count cuts from proven pieces only
// (41 -> 26 launches/iter):
//  - k_resid_elem / k_atd_step ticket fusions (R7/R8-proven).
//  - k_choltrsm = R6 k_chol body (redundant per block) + R6 k_trsm body.
//    L-diag -> Ldiag buffer, y -> yv buffer (kills R7/R8's latent
//    read-raw-while-g0-writes race).
//  - k_cholback = final diag chol + R6 backsolve (one block).
// Lessons baked in: register-array solves must be small standalone kernels
// (R7: fused+unrolled -> 256 VGPR spill; R8: LDS dynamic loops -> latency).

#define NX 4096
#define NEQ 768
#define MUQ 0.1
#define SIGC 0.1
#define NITER 14

__device__ inline double blockReduceSum(double v, double* red){
  int t = threadIdx.x;
  red[t] = v; __syncthreads();
  for (int s = 128; s > 0; s >>= 1){
    if (t < s) red[t] += red[t + s];
    __syncthreads();
  }
  return red[0];
}
__device__ inline double blockReduceMin(double v, double* red){
  int t = threadIdx.x;
  red[t] = v; __syncthreads();
  for (int s = 128; s > 0; s >>= 1){
    if (t < s) red[t] = fmin(red[t], red[t + s]);
    __syncthreads();
  }
  return red[0];
}

// ---------------- dtype detection (R4-proven) ----------------
__global__ void k_detect(const float* __restrict__ Af, int* __restrict__ flag){
  __shared__ int bad;
  if (threadIdx.x == 0) bad = 0;
  __syncthreads();
  for (int i = threadIdx.x; i < 2048; i += 256){
    float f = Af[i];
    if (!(f >= 0.0f && f < 1.0f)) bad = 1;
  }
  __syncthreads();
  if (threadIdx.x == 0) *flag = bad;         // 1 => buffer is fp64
}

__global__ void k_convert(const void* __restrict__ Aptr, const int* __restrict__ flag,
                          float* __restrict__ A32){
  int idx = blockIdx.x * 256 + threadIdx.x;
  if (*flag){
    const double* Ad = (const double*)Aptr;
    for (int s = 0; s < 4; ++s){ int e = idx + s * 786432; A32[e] = (float)Ad[e]; }
  } else {
    const float* Afl = (const float*)Aptr;
    for (int s = 0; s < 4; ++s){ int e = idx + s * 786432; A32[e] = Afl[e]; }
  }
}

// ---------------- setup ----------------
__global__ void k_setup(const float* __restrict__ puz, const void* __restrict__ lz0p,
                        const int* __restrict__ flag,
                        double* q, double* ez, double* z, double* lam, double* nu,
                        unsigned int* cnts){
  int b = blockIdx.x, t = threadIdx.x;
  if (b < 16){
    int k = b * 256 + t;
    q[k] = -(double)puz[k];
    double lv = (*flag) ? ((const double*)lz0p)[k] : (double)((const float*)lz0p)[k];
    ez[k] = exp(lv);
    z[k] = 1.0; lam[k] = 1.0;
  } else {
    for (int i = t; i < NEQ; i += 256) nu[i] = 0.0;
    if (t < 2) cnts[t] = 0;
  }
}

__global__ void k_bvec(const float* __restrict__ A32, const double* __restrict__ ez,
                       double* __restrict__ bv){
  __shared__ double red[256];
  int i = blockIdx.x, t = threadIdx.x;
  const float* Ar = A32 + (size_t)i * NX;
  double acc = 0.0;
  for (int s = 0; s < 16; ++s){ int k = t + s * 256; acc += (double)Ar[k] * ez[k]; }
  acc = blockReduceSum(acc, red);
  if (t == 0) bv[i] = acc;
}

// ---------------- fused residuals + elementwise prep + ADA zeroing ----------
// (R7/R8-proven ticket pattern)
__global__ __launch_bounds__(256) void k_resid_elem(
    const float* __restrict__ A32, const double* __restrict__ nu,
    const double* __restrict__ z, const double* __restrict__ lam,
    const double* __restrict__ bv, const double* __restrict__ q,
    double* __restrict__ atnu_part, double* __restrict__ rp,
    double* __restrict__ gap_slot,
    double* __restrict__ rtil, double* __restrict__ rc,
    double* __restrict__ Di64, float* __restrict__ Di32,
    float* __restrict__ w32, float* __restrict__ ADA,
    unsigned int* __restrict__ cnt){
  __shared__ double red[256];
  __shared__ unsigned int ticket;
  int b = blockIdx.x, t = threadIdx.x;
  if (b < 576){
    size_t idx = ((size_t)b * 256 + t) * 4;
    float4 zf; zf.x = 0.f; zf.y = 0.f; zf.z = 0.f; zf.w = 0.f;
    *(float4*)(ADA + idx) = zf;                 // 576*1024 = 589824 floats
  }
  if (b < 64){
    int kblk = b & 15, ch = b >> 4;
    int k = kblk * 256 + t;
    double acc = 0.0;
    int i0 = ch * 192;
    for (int i = i0; i < i0 + 192; ++i) acc += (double)A32[(size_t)i * NX + k] * nu[i];
    atnu_part[ch * NX + k] = acc;
  } else if (b < 832){
    int i = b - 64;
    const float* Ar = A32 + (size_t)i * NX;
    double acc = 0.0;
    for (int s = 0; s < 16; ++s){ int k = t + s * 256; acc += (double)Ar[k] * z[k]; }
    acc = blockReduceSum(acc, red);
    if (t == 0) rp[i] = acc - bv[i];
  } else {
    double acc = 0.0;
    for (int s = 0; s < 16; ++s){ int k = t + s * 256; acc += z[k] * lam[k]; }
    acc = blockReduceSum(acc, red);
    if (t == 0) *gap_slot = acc;
  }
  __threadfence();
  __syncthreads();
  if (t == 0) ticket = atomicAdd(cnt, 1u);
  __syncthreads();
  if (ticket != 832u) return;
  __threadfence();
  double gap = (*gap_slot) * (1.0 / NX);
  for (int k = t; k < NX; k += 256){
    double atnu = atnu_part[k] + atnu_part[NX + k]
                + atnu_part[2*NX + k] + atnu_part[3*NX + k];
    double zk = z[k], lk = lam[k];
    double rd  = MUQ * zk + q[k] - lk + atnu;
    double rcv = zk * lk - SIGC * gap;
    double di  = 1.0 / (MUQ + lk / zk);
    double rt  = -rd - rcv / zk;
    rtil[k] = rt; rc[k] = rcv; Di64[k] = di;
    Di32[k] = (float)di;
    w32[k]  = (float)(rt * di);
  }
  if (t == 0) *cnt = 0u;
}

// blocks 0..155: lower tiles (78 pairs x ksplit2); 156..923: rhs rows (proven)
__global__ __launch_bounds__(256) void k_ada(const float* __restrict__ A32,
                      const float* __restrict__ Di32, const float* __restrict__ w32,
                      const double* __restrict__ rp,
                      float* __restrict__ ADA, float* __restrict__ rhs){
  __shared__ float As[16][68], Bs[16][68];
  __shared__ double red[256];
  int b = blockIdx.x, tid = threadIdx.x;
  if (b < 156){
    int pr = b >> 1, ks = b & 1;
    int ti = 0;
    while ((ti + 1) * (ti + 2) / 2 <= pr) ++ti;
    int tj = pr - ti * (ti + 1) / 2;
    int lr = tid >> 2, lq = tid & 3;
    int tx = tid & 15, ty = tid >> 4;
    const float* Arow = A32 + (size_t)(ti * 64 + lr) * NX;
    const float* Brow = A32 + (size_t)(tj * 64 + lr) * NX;
    float c44[4][4];
#pragma unroll
    for (int i = 0; i < 4; ++i)
#pragma unroll
      for (int j = 0; j < 4; ++j) c44[i][j] = 0.0f;
    int k0 = ks * 2048;
    for (int kk = k0; kk < k0 + 2048; kk += 16){
#pragma unroll
      for (int s = 0; s < 4; ++s){
        int kc = kk + lq * 4 + s;
        As[lq * 4 + s][lr] = Arow[kc];
        Bs[lq * 4 + s][lr] = Brow[kc] * Di32[kc];
      }
      __syncthreads();
#pragma unroll
      for (int m = 0; m < 16; ++m){
        float4 aa = *(const float4*)&As[m][ty * 4];
        float4 bb = *(const float4*)&Bs[m][tx * 4];
        float a4[4] = {aa.x, aa.y, aa.z, aa.w};
        float b4[4] = {bb.x, bb.y, bb.z, bb.w};
#pragma unroll
        for (int i = 0; i < 4; ++i)
#pragma unroll
          for (int j = 0; j < 4; ++j) c44[i][j] += a4[i] * b4[j];
      }
      __syncthreads();
    }
#pragma unroll
    for (int i = 0; i < 4; ++i){
      int row = ti * 64 + ty * 4 + i;
#pragma unroll
      for (int j = 0; j < 4; ++j){
        int col = tj * 64 + tx * 4 + j;
        atomicAdd(&ADA[(size_t)row * 768 + col], c44[i][j]);
      }
    }
  } else {
    int r = b - 156;
    const float* Ar = A32 + (size_t)r * NX;
    double acc = 0.0;
    for (int s = 0; s < 16; ++s){
      int k = tid + s * 256;
      acc += (double)Ar[k] * (double)w32[k];
    }
    acc = blockReduceSum(acc, red);
    if (tid == 0) rhs[r] = (float)(acc + rp[r]);
  }
}

// ---------------- fused chol+trsm per panel (R6 bodies, redundant chol) -----
// grid 12-p, 64 threads. Every block: register chol of diag (R6 k_chol body)
// + rhs fwd-elim into local rvs. g==0 writes Ldiag[p], yv[p-block].
// g>0: R6 k_trsm body using local L (LDS) and local y, writes trsm tile to
// ADA[r,p] and rhs[r-block] -= L21 y_p. No cross-block reads-after-writes.
__global__ __launch_bounds__(64) void k_choltrsm(float* __restrict__ ADA,
      float* __restrict__ rhs, float* __restrict__ Ldiag,
      float* __restrict__ yv, int p){
  int g = blockIdx.x;
  int t = threadIdx.x;
  int base = p * 64;
  __shared__ float colr[64];
  __shared__ float rvs[64];
  __shared__ float Ls[64][65];
  __shared__ float Xs[64][65];

  // ---- redundant register chol of diag tile (R6 k_chol body, verbatim) ----
  {
    float R[64];
    const float* src = ADA + (size_t)(base + t) * 768 + base;
#pragma unroll
    for (int c = 0; c < 64; ++c) R[c] = (c <= t) ? src[c] : 0.0f;
    rvs[t] = rhs[base + t];
    __syncthreads();
#pragma unroll
    for (int j = 0; j < 64; ++j){
      colr[t] = R[j];
      __syncthreads();
      float v   = fmaxf(colr[j], 1e-12f);
      float inv = 1.0f / v;
      float s   = sqrtf(v);
      float rvj = rvs[j];
      float ar  = R[j] * inv;
      __syncthreads();                      // all reads done before writes
      if (t > j){
#pragma unroll
        for (int c = j + 1; c < 64; ++c)
          R[c] -= ar * colr[c];
        rvs[t] -= ar * rvj;
        R[j] = ar * s;
      } else if (t == j){
        R[j] = s;
        rvs[j] = rvj * inv * s;
      }
      __syncthreads();
    }
    // publish L rows to LDS for the trsm phase; g==0 persists to Ldiag/yv
#pragma unroll
    for (int c = 0; c < 64; ++c) Ls[t][c] = (c <= t) ? R[c] : 0.0f;
  }
  __syncthreads();

  if (g == 0){
    for (int c = 0; c < 64; ++c)
      Ldiag[(size_t)p * 4096 + t * 64 + c] = Ls[t][c];
    yv[base + t] = rvs[t];
    return;
  }

  // ---- R6 k_trsm body (local Ls, local rvs as y_p) ----
  int r0 = base + g * 64;
  for (int s = 0; s < 64; ++s)
    Xs[s][t] = ADA[(size_t)(r0 + s) * 768 + base + t];
  __syncthreads();
  float X[64];
#pragma unroll
  for (int c = 0; c < 64; ++c) X[c] = Xs[t][c];
#pragma unroll
  for (int j = 0; j < 64; ++j){
    float xj = X[j] / Ls[j][j];
    X[j] = xj;
#pragma unroll
    for (int c = j + 1; c < 64; ++c) X[c] -= xj * Ls[c][j];
  }
  float racc = 0.0f;
#pragma unroll
  for (int c = 0; c < 64; ++c){ Xs[t][c] = X[c]; racc += X[c] * rvs[c]; }
  __syncthreads();
  for (int s = 0; s < 64; ++s)
    ADA[(size_t)(r0 + s) * 768 + base + t] = Xs[s][t];
  rhs[r0 + t] -= racc;
}

// trailing update, lower tiles: C -= L21_i * L21_j^T  (R6-proven, verbatim)
__global__ __launch_bounds__(256) void k_syrk(float* __restrict__ ADA, int p){
  int base = p * 64, s0 = base + 64;
  int b = blockIdx.x, tid = threadIdx.x;
  int ti = 0;
  while ((ti + 1) * (ti + 2) / 2 <= b) ++ti;
  int tj = b - ti * (ti + 1) / 2;
  int r0 = s0 + ti * 64, c0 = s0 + tj * 64;
  __shared__ float LAT[64][68], LBT[64][68];    // [k][row]
  for (int idx = tid; idx < 64 * 64; idx += 256){
    int r = idx >> 6, c = idx & 63;
    LAT[c][r] = ADA[(size_t)(r0 + r) * 768 + base + c];
    LBT[c][r] = ADA[(size_t)(c0 + r) * 768 + base + c];
  }
  __syncthreads();
  int tx = tid & 15, ty = tid >> 4;
  float c44[4][4];
#pragma unroll
  for (int i = 0; i < 4; ++i)
#pragma unroll
    for (int j = 0; j < 4; ++j) c44[i][j] = 0.0f;
  for (int m = 0; m < 64; ++m){
    float4 aa = *(const float4*)&LAT[m][ty * 4];
    float4 bb = *(const float4*)&LBT[m][tx * 4];
    float a4[4] = {aa.x, aa.y, aa.z, aa.w};
    float b4[4] = {bb.x, bb.y, bb.z, bb.w};
#pragma unroll
    for (int i = 0; i < 4; ++i)
#pragma unroll
      for (int j = 0; j < 4; ++j) c44[i][j] += a4[i] * b4[j];
  }
#pragma unroll
  for (int i = 0; i < 4; ++i){
    int row = r0 + ty * 4 + i;
#pragma unroll
    for (int j = 0; j < 4; ++j){
      int col = c0 + tx * 4 + j;
      ADA[(size_t)row * 768 + col] -= c44[i][j];
    }
  }
}

// ---------------- final diag chol (p=11) + R6 backsolve, one block ---------
__global__ __launch_bounds__(64) void k_cholback(const float* __restrict__ ADA,
      const float* __restrict__ rhs, float* __restrict__ Ldiag,
      float* __restrict__ yv, float* __restrict__ dnu32){
  int t = threadIdx.x;
  const int base = 704;                       // 11*64
  __shared__ float colr[64];
  __shared__ float rvs[64];
  __shared__ float Lb[64][65];
  __shared__ float ysl[64], xsh[64];

  // chol of panel 11 diag (R6 k_chol body)
  {
    float R[64];
    const float* src = ADA + (size_t)(base + t) * 768 + base;
#pragma unroll
    for (int c = 0; c < 64; ++c) R[c] = (c <= t) ? src[c] : 0.0f;
    rvs[t] = rhs[base + t];
    __syncthreads();
#pragma unroll
    for (int j = 0; j < 64; ++j){
      colr[t] = R[j];
      __syncthreads();
      float v   = fmaxf(colr[j], 1e-12f);
      float inv = 1.0f / v;
      float s   = sqrtf(v);
      float rvj = rvs[j];
      float ar  = R[j] * inv;
      __syncthreads();
      if (t > j){
#pragma unroll
        for (int c = j + 1; c < 64; ++c)
          R[c] -= ar * colr[c];
        rvs[t] -= ar * rvj;
        R[j] = ar * s;
      } else if (t == j){
        R[j] = s;
        rvs[j] = rvj * inv * s;
      }
      __syncthreads();
    }
    for (int c = 0; c < 64; ++c)
      Ldiag[(size_t)11 * 4096 + t * 64 + c] = (c <= t) ? R[c] : 0.0f;
    yv[base + t] = rvs[t];
  }
  __syncthreads();

  // blocked backward solve  L^T dnu = y  (R6 k_backsolve body; Ldiag + yv)
  for (int bb = 11; bb >= 0; --bb){
    int b2 = bb * 64;
    for (int s = 0; s < 64; ++s)
      Lb[s][t] = Ldiag[(size_t)bb * 4096 + s * 64 + t];
    ysl[t] = yv[b2 + t];
    __syncthreads();
    for (int j = 63; j >= 0; --j){
      if (t == j) xsh[j] = ysl[j] / Lb[j][j];
      __syncthreads();
      if (t < j) ysl[t] -= Lb[j][t] * xsh[j];
      __syncthreads();
    }
    dnu32[b2 + t] = xsh[t];
    for (int r = t; r < b2; r += 64){         // y_above -= L21^T x
      float acc = 0.0f;
      for (int k = 0; k < 64; ++k)
        acc += ADA[(size_t)(b2 + k) * 768 + r] * xsh[k];
      yv[r] -= acc;
    }
    __syncthreads();
  }
}

// ---------------- fused A^T dnu + step + update (R7/R8-proven ticket) ------
__global__ __launch_bounds__(256) void k_atd_step(
    const float* __restrict__ A32, const float* __restrict__ dnu32,
    float* __restrict__ atd_part,
    const double* __restrict__ rtil, const double* __restrict__ rc,
    const double* __restrict__ Di64,
    double* __restrict__ z, double* __restrict__ lam, double* __restrict__ nu,
    unsigned int* __restrict__ cnt){
  __shared__ double red[256];
  __shared__ unsigned int ticket;
  int bx = blockIdx.x, t = threadIdx.x;
  int kblk = bx & 15, ch = bx >> 4;
  int k = kblk * 256 + t;
  double acc = 0.0;
  int i0 = ch * 192;
  for (int i = i0; i < i0 + 192; ++i)
    acc += (double)A32[(size_t)i * NX + k] * (double)dnu32[i];
  atd_part[ch * NX + k] = (float)acc;
  __threadfence();
  __syncthreads();
  if (t == 0) ticket = atomicAdd(cnt, 1u);
  __syncthreads();
  if (ticket != 63u) return;
  __threadfence();
  double dzl[16], dll[16];
  double amin = INFINITY;
#pragma unroll
  for (int s = 0; s < 16; ++s){
    int kk = t + s * 256;
    double atd = (double)atd_part[kk] + (double)atd_part[NX + kk]
               + (double)atd_part[2*NX + kk] + (double)atd_part[3*NX + kk];
    double dzk = (rtil[kk] - atd) * Di64[kk];
    double zk = z[kk], lk = lam[kk];
    double dlk = (-rc[kk] - lk * dzk) / zk;
    dzl[s] = dzk; dll[s] = dlk;
    if (dzk < 0.0) amin = fmin(amin, -zk / dzk);
    if (dlk < 0.0) amin = fmin(amin, -lk / dlk);
  }
  amin = blockReduceMin(amin, red);
  double alpha = fmin(1.0, 0.99 * amin);
#pragma unroll
  for (int s = 0; s < 16; ++s){
    int kk = t + s * 256;
    z[kk]   += alpha * dzl[s];
    lam[kk] += alpha * dll[s];
  }
  for (int i = t; i < NEQ; i += 256) nu[i] += alpha * (double)dnu32[i];
  if (t == 0) *cnt = 0u;
}

__global__ void k_out(const double* __restrict__ z, float* __restrict__ out){
  int k = blockIdx.x * 256 + threadIdx.x;
  out[k] = (float)z[k];
}

// ---------------- host ----------------
extern "C" void kernel_launch(void* const* d_in, const int* in_sizes, int n_in,
                              void* d_out, int out_size, void* d_ws, size_t ws_size,
                              hipStream_t stream){
  const float* puz  = (const float*)d_in[0];
  const void*  Ap   = d_in[1];
  const void*  lz0p = d_in[2];
  float* out = (float*)d_out;
  char* w = (char*)d_ws;

  size_t o = 0;
  float* A32 = (float*)(w + o);        o += (size_t)NEQ * NX * 4;     // 12.58 MB
  float* ADA = (float*)(w + o);        o += (size_t)768 * 768 * 4;    // 2.36 MB
  float* Ldiag = (float*)(w + o);      o += 12ull * 4096 * 4;         // 196 KB
  double* q    = (double*)(w + o);     o += NX * 8;
  double* ez   = (double*)(w + o);     o += NX * 8;
  double* z    = (double*)(w + o);     o += NX * 8;
  double* lam  = (double*)(w + o);     o += NX * 8;
  double* rtil = (double*)(w + o);     o += NX * 8;
  double* rc   = (double*)(w + o);     o += NX * 8;
  double* Di64 = (double*)(w + o);     o += NX * 8;
  double* atnu = (double*)(w + o);     o += 4ull * NX * 8;
  double* nu   = (double*)(w + o);     o += NEQ * 8;
  double* bv   = (double*)(w + o);     o += NEQ * 8;
  double* rp   = (double*)(w + o);     o += NEQ * 8;
  double* gap_slot = (double*)(w + o); o += 8;
  float* Di32  = (float*)(w + o);      o += NX * 4;
  float* w32   = (float*)(w + o);      o += NX * 4;
  float* atd_part = (float*)(w + o);   o += 4ull * NX * 4;
  float* rhs   = (float*)(w + o);      o += NEQ * 4;
  float* yv    = (float*)(w + o);      o += NEQ * 4;
  float* dnu32 = (float*)(w + o);      o += NEQ * 4;
  int*   dflag = (int*)(w + o);        o += 16;
  unsigned int* cnts = (unsigned int*)(w + o); o += 16;
  (void)ws_size; (void)in_sizes; (void)n_in; (void)out_size;   // ~15.7 MB used

  k_detect<<<1, 256, 0, stream>>>((const float*)Ap, dflag);
  k_convert<<<3072, 256, 0, stream>>>(Ap, dflag, A32);
  k_setup<<<17, 256, 0, stream>>>(puz, lz0p, dflag, q, ez, z, lam, nu, cnts);
  k_bvec<<<768, 256, 0, stream>>>(A32, ez, bv);

  for (int it = 0; it < NITER; ++it){
    k_resid_elem<<<833, 256, 0, stream>>>(A32, nu, z, lam, bv, q,
                                          atnu, rp, gap_slot,
                                          rtil, rc, Di64, Di32, w32, ADA, cnts);
    k_ada<<<924, 256, 0, stream>>>(A32, Di32, w32, rp, ADA, rhs);
    for (int p = 0; p < 11; ++p){
      k_choltrsm<<<12 - p, 64, 0, stream>>>(ADA, rhs, Ldiag, yv, p);
      int nt = 11 - p;
      k_syrk<<<nt * (nt + 1) / 2, 256, 0, stream>>>(ADA, p);
    }
    k_cholback<<<1, 64, 0, stream>>>(ADA, rhs, Ldiag, yv, dnu32);
    k_atd_step<<<64, 256, 0, stream>>>(A32, dnu32, atd_part,
                                       rtil, rc, Di64, z, lam, nu, cnts + 1);
  }
  k_out<<<16, 256, 0, stream>>>(z, out);
}

// Round 10
// 14635.074 us; speedup vs baseline: 2.1037x; 1.3082x over previous
//
#include <hip/hip_runtime.h>
#include <math.h>

// dQPEq: primal-dual IPM for  min 0.5*mu*||z||^2 + q^T z  s.t. Az=b, z>=0
// mu=0.1, sigma=0.1. fp64 state/residuals, fp32 A/Schur/Cholesky. NITER=14.
// R10: A/B vs R9 — revert the ticket fusions (per-block device-scope
// __threadfence in 833+64 blocks => per-block L2 writebacks on non-coherent
// XCD L2s; launch boundaries provide the same visibility once per kernel),
// keep the fence-free k_choltrsm/k_cholback merges (R9-verified arithmetic,
// absmax bit-matched R6). vs R6: -12 launches/iter; vs R9: no tickets.

#define NX 4096
#define NEQ 768
#define MUQ 0.1
#define SIGC 0.1
#define NITER 14

__device__ inline double blockReduceSum(double v, double* red){
  int t = threadIdx.x;
  red[t] = v; __syncthreads();
  for (int s = 128; s > 0; s >>= 1){
    if (t < s) red[t] += red[t + s];
    __syncthreads();
  }
  return red[0];
}
__device__ inline double blockReduceMin(double v, double* red){
  int t = threadIdx.x;
  red[t] = v; __syncthreads();
  for (int s = 128; s > 0; s >>= 1){
    if (t < s) red[t] = fmin(red[t], red[t + s]);
    __syncthreads();
  }
  return red[0];
}

// ---------------- dtype detection (R4-proven) ----------------
__global__ void k_detect(const float* __restrict__ Af, int* __restrict__ flag){
  __shared__ int bad;
  if (threadIdx.x == 0) bad = 0;
  __syncthreads();
  for (int i = threadIdx.x; i < 2048; i += 256){
    float f = Af[i];
    if (!(f >= 0.0f && f < 1.0f)) bad = 1;
  }
  __syncthreads();
  if (threadIdx.x == 0) *flag = bad;         // 1 => buffer is fp64
}

__global__ void k_convert(const void* __restrict__ Aptr, const int* __restrict__ flag,
                          float* __restrict__ A32){
  int idx = blockIdx.x * 256 + threadIdx.x;
  if (*flag){
    const double* Ad = (const double*)Aptr;
    for (int s = 0; s < 4; ++s){ int e = idx + s * 786432; A32[e] = (float)Ad[e]; }
  } else {
    const float* Afl = (const float*)Aptr;
    for (int s = 0; s < 4; ++s){ int e = idx + s * 786432; A32[e] = Afl[e]; }
  }
}

// ---------------- setup ----------------
__global__ void k_setup(const float* __restrict__ puz, const void* __restrict__ lz0p,
                        const int* __restrict__ flag,
                        double* q, double* ez, double* z, double* lam, double* nu){
  int b = blockIdx.x, t = threadIdx.x;
  if (b < 16){
    int k = b * 256 + t;
    q[k] = -(double)puz[k];
    double lv = (*flag) ? ((const double*)lz0p)[k] : (double)((const float*)lz0p)[k];
    ez[k] = exp(lv);
    z[k] = 1.0; lam[k] = 1.0;
  } else {
    for (int i = t; i < NEQ; i += 256) nu[i] = 0.0;
  }
}

__global__ void k_bvec(const float* __restrict__ A32, const double* __restrict__ ez,
                       double* __restrict__ bv){
  __shared__ double red[256];
  int i = blockIdx.x, t = threadIdx.x;
  const float* Ar = A32 + (size_t)i * NX;
  double acc = 0.0;
  for (int s = 0; s < 16; ++s){ int k = t + s * 256; acc += (double)Ar[k] * ez[k]; }
  acc = blockReduceSum(acc, red);
  if (t == 0) bv[i] = acc;
}

// ---------------- per-iteration (R6-verbatim bodies) ----------------
// blocks 0..63: atnu partials; 64..831: rp rows; 832: gap
__global__ void k_resid(const float* __restrict__ A32, const double* __restrict__ nu,
                        const double* __restrict__ z, const double* __restrict__ lam,
                        const double* __restrict__ bv,
                        double* __restrict__ atnu_part, double* __restrict__ rp,
                        double* __restrict__ gap_slot){
  __shared__ double red[256];
  int b = blockIdx.x, t = threadIdx.x;
  if (b < 64){
    int kblk = b & 15, ch = b >> 4;
    int k = kblk * 256 + t;
    double acc = 0.0;
    int i0 = ch * 192;
    for (int i = i0; i < i0 + 192; ++i) acc += (double)A32[(size_t)i * NX + k] * nu[i];
    atnu_part[ch * NX + k] = acc;
  } else if (b < 832){
    int i = b - 64;
    const float* Ar = A32 + (size_t)i * NX;
    double acc = 0.0;
    for (int s = 0; s < 16; ++s){ int k = t + s * 256; acc += (double)Ar[k] * z[k]; }
    acc = blockReduceSum(acc, red);
    if (t == 0) rp[i] = acc - bv[i];
  } else {
    double acc = 0.0;
    for (int s = 0; s < 16; ++s){ int k = t + s * 256; acc += z[k] * lam[k]; }
    acc = blockReduceSum(acc, red);
    if (t == 0) *gap_slot = acc;
  }
}

// blocks 0..15: elementwise prep; 16..591: zero ADA (float4)
__global__ void k_elem(const double* __restrict__ atnu_part, const double* __restrict__ q,
                       const double* __restrict__ z, const double* __restrict__ lam,
                       const double* __restrict__ gap_slot,
                       double* __restrict__ rtil, double* __restrict__ rc,
                       double* __restrict__ Di64, float* __restrict__ Di32,
                       float* __restrict__ w32, float* __restrict__ ADA){
  if (blockIdx.x >= 16){
    size_t idx = ((size_t)(blockIdx.x - 16) * 256 + threadIdx.x) * 4;
    float4 zf; zf.x = 0.f; zf.y = 0.f; zf.z = 0.f; zf.w = 0.f;
    *(float4*)(ADA + idx) = zf;
    return;
  }
  int k = blockIdx.x * 256 + threadIdx.x;
  double atnu = atnu_part[k] + atnu_part[NX + k] + atnu_part[2*NX + k] + atnu_part[3*NX + k];
  double zk = z[k], lk = lam[k];
  double rd  = MUQ * zk + q[k] - lk + atnu;
  double gap = (*gap_slot) * (1.0 / NX);
  double rcv = zk * lk - SIGC * gap;
  double di  = 1.0 / (MUQ + lk / zk);
  double rt  = -rd - rcv / zk;
  rtil[k] = rt; rc[k] = rcv; Di64[k] = di;
  Di32[k] = (float)di;
  w32[k]  = (float)(rt * di);
}

// blocks 0..155: lower tiles (78 pairs x ksplit2); 156..923: rhs rows (proven)
__global__ __launch_bounds__(256) void k_ada(const float* __restrict__ A32,
                      const float* __restrict__ Di32, const float* __restrict__ w32,
                      const double* __restrict__ rp,
                      float* __restrict__ ADA, float* __restrict__ rhs){
  __shared__ float As[16][68], Bs[16][68];
  __shared__ double red[256];
  int b = blockIdx.x, tid = threadIdx.x;
  if (b < 156){
    int pr = b >> 1, ks = b & 1;
    int ti = 0;
    while ((ti + 1) * (ti + 2) / 2 <= pr) ++ti;
    int tj = pr - ti * (ti + 1) / 2;
    int lr = tid >> 2, lq = tid & 3;
    int tx = tid & 15, ty = tid >> 4;
    const float* Arow = A32 + (size_t)(ti * 64 + lr) * NX;
    const float* Brow = A32 + (size_t)(tj * 64 + lr) * NX;
    float c44[4][4];
#pragma unroll
    for (int i = 0; i < 4; ++i)
#pragma unroll
      for (int j = 0; j < 4; ++j) c44[i][j] = 0.0f;
    int k0 = ks * 2048;
    for (int kk = k0; kk < k0 + 2048; kk += 16){
#pragma unroll
      for (int s = 0; s < 4; ++s){
        int kc = kk + lq * 4 + s;
        As[lq * 4 + s][lr] = Arow[kc];
        Bs[lq * 4 + s][lr] = Brow[kc] * Di32[kc];
      }
      __syncthreads();
#pragma unroll
      for (int m = 0; m < 16; ++m){
        float4 aa = *(const float4*)&As[m][ty * 4];
        float4 bb = *(const float4*)&Bs[m][tx * 4];
        float a4[4] = {aa.x, aa.y, aa.z, aa.w};
        float b4[4] = {bb.x, bb.y, bb.z, bb.w};
#pragma unroll
        for (int i = 0; i < 4; ++i)
#pragma unroll
          for (int j = 0; j < 4; ++j) c44[i][j] += a4[i] * b4[j];
      }
      __syncthreads();
    }
#pragma unroll
    for (int i = 0; i < 4; ++i){
      int row = ti * 64 + ty * 4 + i;
#pragma unroll
      for (int j = 0; j < 4; ++j){
        int col = tj * 64 + tx * 4 + j;
        atomicAdd(&ADA[(size_t)row * 768 + col], c44[i][j]);
      }
    }
  } else {
    int r = b - 156;
    const float* Ar = A32 + (size_t)r * NX;
    double acc = 0.0;
    for (int s = 0; s < 16; ++s){
      int k = tid + s * 256;
      acc += (double)Ar[k] * (double)w32[k];
    }
    acc = blockReduceSum(acc, red);
    if (tid == 0) rhs[r] = (float)(acc + rp[r]);
  }
}

// ---------------- fused chol+trsm per panel (R9-verified arithmetic) --------
// grid 12-p, 64 threads. Every block: register chol of diag (R6 k_chol body)
// + rhs fwd-elim into local rvs. g==0 writes Ldiag[p], yv[p-block].
// g>0: R6 k_trsm body with local Ls/rvs; writes trsm tile + rhs update.
__global__ __launch_bounds__(64) void k_choltrsm(float* __restrict__ ADA,
      float* __restrict__ rhs, float* __restrict__ Ldiag,
      float* __restrict__ yv, int p){
  int g = blockIdx.x;
  int t = threadIdx.x;
  int base = p * 64;
  __shared__ float colr[64];
  __shared__ float rvs[64];
  __shared__ float Ls[64][65];
  __shared__ float Xs[64][65];

  {
    float R[64];
    const float* src = ADA + (size_t)(base + t) * 768 + base;
#pragma unroll
    for (int c = 0; c < 64; ++c) R[c] = (c <= t) ? src[c] : 0.0f;
    rvs[t] = rhs[base + t];
    __syncthreads();
#pragma unroll
    for (int j = 0; j < 64; ++j){
      colr[t] = R[j];
      __syncthreads();
      float v   = fmaxf(colr[j], 1e-12f);
      float inv = 1.0f / v;
      float s   = sqrtf(v);
      float rvj = rvs[j];
      float ar  = R[j] * inv;
      __syncthreads();
      if (t > j){
#pragma unroll
        for (int c = j + 1; c < 64; ++c)
          R[c] -= ar * colr[c];
        rvs[t] -= ar * rvj;
        R[j] = ar * s;
      } else if (t == j){
        R[j] = s;
        rvs[j] = rvj * inv * s;
      }
      __syncthreads();
    }
#pragma unroll
    for (int c = 0; c < 64; ++c) Ls[t][c] = (c <= t) ? R[c] : 0.0f;
  }
  __syncthreads();

  if (g == 0){
    for (int c = 0; c < 64; ++c)
      Ldiag[(size_t)p * 4096 + t * 64 + c] = Ls[t][c];
    yv[base + t] = rvs[t];
    return;
  }

  int r0 = base + g * 64;
  for (int s = 0; s < 64; ++s)
    Xs[s][t] = ADA[(size_t)(r0 + s) * 768 + base + t];
  __syncthreads();
  float X[64];
#pragma unroll
  for (int c = 0; c < 64; ++c) X[c] = Xs[t][c];
#pragma unroll
  for (int j = 0; j < 64; ++j){
    float xj = X[j] / Ls[j][j];
    X[j] = xj;
#pragma unroll
    for (int c = j + 1; c < 64; ++c) X[c] -= xj * Ls[c][j];
  }
  float racc = 0.0f;
#pragma unroll
  for (int c = 0; c < 64; ++c){ Xs[t][c] = X[c]; racc += X[c] * rvs[c]; }
  __syncthreads();
  for (int s = 0; s < 64; ++s)
    ADA[(size_t)(r0 + s) * 768 + base + t] = Xs[s][t];
  rhs[r0 + t] -= racc;
}

// trailing update, lower tiles: C -= L21_i * L21_j^T  (R6-proven, verbatim)
__global__ __launch_bounds__(256) void k_syrk(float* __restrict__ ADA, int p){
  int base = p * 64, s0 = base + 64;
  int b = blockIdx.x, tid = threadIdx.x;
  int ti = 0;
  while ((ti + 1) * (ti + 2) / 2 <= b) ++ti;
  int tj = b - ti * (ti + 1) / 2;
  int r0 = s0 + ti * 64, c0 = s0 + tj * 64;
  __shared__ float LAT[64][68], LBT[64][68];    // [k][row]
  for (int idx = tid; idx < 64 * 64; idx += 256){
    int r = idx >> 6, c = idx & 63;
    LAT[c][r] = ADA[(size_t)(r0 + r) * 768 + base + c];
    LBT[c][r] = ADA[(size_t)(c0 + r) * 768 + base + c];
  }
  __syncthreads();
  int tx = tid & 15, ty = tid >> 4;
  float c44[4][4];
#pragma unroll
  for (int i = 0; i < 4; ++i)
#pragma unroll
    for (int j = 0; j < 4; ++j) c44[i][j] = 0.0f;
  for (int m = 0; m < 64; ++m){
    float4 aa = *(const float4*)&LAT[m][ty * 4];
    float4 bb = *(const float4*)&LBT[m][tx * 4];
    float a4[4] = {aa.x, aa.y, aa.z, aa.w};
    float b4[4] = {bb.x, bb.y, bb.z, bb.w};
#pragma unroll
    for (int i = 0; i < 4; ++i)
#pragma unroll
      for (int j = 0; j < 4; ++j) c44[i][j] += a4[i] * b4[j];
  }
#pragma unroll
  for (int i = 0; i < 4; ++i){
    int row = r0 + ty * 4 + i;
#pragma unroll
    for (int j = 0; j < 4; ++j){
      int col = c0 + tx * 4 + j;
      ADA[(size_t)row * 768 + col] -= c44[i][j];
    }
  }
}

// ---------------- final diag chol (p=11) + R6 backsolve, one block ---------
__global__ __launch_bounds__(64) void k_cholback(const float* __restrict__ ADA,
      const float* __restrict__ rhs, float* __restrict__ Ldiag,
      float* __restrict__ yv, float* __restrict__ dnu32){
  int t = threadIdx.x;
  const int base = 704;                       // 11*64
  __shared__ float colr[64];
  __shared__ float rvs[64];
  __shared__ float Lb[64][65];
  __shared__ float ysl[64], xsh[64];

  {
    float R[64];
    const float* src = ADA + (size_t)(base + t) * 768 + base;
#pragma unroll
    for (int c = 0; c < 64; ++c) R[c] = (c <= t) ? src[c] : 0.0f;
    rvs[t] = rhs[base + t];
    __syncthreads();
#pragma unroll
    for (int j = 0; j < 64; ++j){
      colr[t] = R[j];
      __syncthreads();
      float v   = fmaxf(colr[j], 1e-12f);
      float inv = 1.0f / v;
      float s   = sqrtf(v);
      float rvj = rvs[j];
      float ar  = R[j] * inv;
      __syncthreads();
      if (t > j){
#pragma unroll
        for (int c = j + 1; c < 64; ++c)
          R[c] -= ar * colr[c];
        rvs[t] -= ar * rvj;
        R[j] = ar * s;
      } else if (t == j){
        R[j] = s;
        rvs[j] = rvj * inv * s;
      }
      __syncthreads();
    }
    for (int c = 0; c < 64; ++c)
      Ldiag[(size_t)11 * 4096 + t * 64 + c] = (c <= t) ? R[c] : 0.0f;
    yv[base + t] = rvs[t];
  }
  __syncthreads();

  for (int bb = 11; bb >= 0; --bb){
    int b2 = bb * 64;
    for (int s = 0; s < 64; ++s)
      Lb[s][t] = Ldiag[(size_t)bb * 4096 + s * 64 + t];
    ysl[t] = yv[b2 + t];
    __syncthreads();
    for (int j = 63; j >= 0; --j){
      if (t == j) xsh[j] = ysl[j] / Lb[j][j];
      __syncthreads();
      if (t < j) ysl[t] -= Lb[j][t] * xsh[j];
      __syncthreads();
    }
    dnu32[b2 + t] = xsh[t];
    for (int r = t; r < b2; r += 64){         // y_above -= L21^T x
      float acc = 0.0f;
      for (int k = 0; k < 64; ++k)
        acc += ADA[(size_t)(b2 + k) * 768 + r] * xsh[k];
      yv[r] -= acc;
    }
    __syncthreads();
  }
}

// A^T dnu partials (non-atomic), fp64 accumulate (R6-verbatim)
__global__ void k_atd(const float* __restrict__ A32, const float* __restrict__ dnu32,
                      float* __restrict__ atd_part){
  int bx = blockIdx.x;
  int kblk = bx & 15, ch = bx >> 4;
  int k = kblk * 256 + threadIdx.x;
  double acc = 0.0;
  int i0 = ch * 192;
  for (int i = i0; i < i0 + 192; ++i)
    acc += (double)A32[(size_t)i * NX + k] * (double)dnu32[i];
  atd_part[ch * NX + k] = (float)acc;
}

__global__ void k_step(const double* __restrict__ rtil, const double* __restrict__ rc,
                       const double* __restrict__ Di64, const double* __restrict__ z,
                       const double* __restrict__ lam, const float* __restrict__ atd_part,
                       double* __restrict__ dz, double* __restrict__ dlam,
                       double* __restrict__ amin_part){
  __shared__ double red[256];
  int k = blockIdx.x * 256 + threadIdx.x;
  double atd = (double)atd_part[k] + (double)atd_part[NX + k]
             + (double)atd_part[2*NX + k] + (double)atd_part[3*NX + k];
  double dzk = (rtil[k] - atd) * Di64[k];
  double zk = z[k], lk = lam[k];
  double dlk = (-rc[k] - lk * dzk) / zk;
  dz[k] = dzk; dlam[k] = dlk;
  double a = INFINITY;
  if (dzk < 0.0) a = -zk / dzk;
  if (dlk < 0.0) a = fmin(a, -lk / dlk);
  a = blockReduceMin(a, red);
  if (threadIdx.x == 0) amin_part[blockIdx.x] = a;
}

__global__ void k_update(double* __restrict__ z, double* __restrict__ lam,
                         double* __restrict__ nu,
                         const double* __restrict__ dz, const double* __restrict__ dlam,
                         const float* __restrict__ dnu32,
                         const double* __restrict__ amin_part){
  double m = amin_part[0];
  for (int i = 1; i < 16; ++i) m = fmin(m, amin_part[i]);
  double alpha = fmin(1.0, 0.99 * m);
  int b = blockIdx.x, t = threadIdx.x;
  if (b < 16){
    int k = b * 256 + t;
    z[k]   += alpha * dz[k];
    lam[k] += alpha * dlam[k];
  } else {
    for (int i = t; i < NEQ; i += 256) nu[i] += alpha * (double)dnu32[i];
  }
}

__global__ void k_out(const double* __restrict__ z, float* __restrict__ out){
  int k = blockIdx.x * 256 + threadIdx.x;
  out[k] = (float)z[k];
}

// ---------------- host ----------------
extern "C" void kernel_launch(void* const* d_in, const int* in_sizes, int n_in,
                              void* d_out, int out_size, void* d_ws, size_t ws_size,
                              hipStream_t stream){
  const float* puz  = (const float*)d_in[0];
  const void*  Ap   = d_in[1];
  const void*  lz0p = d_in[2];
  float* out = (float*)d_out;
  char* w = (char*)d_ws;

  size_t o = 0;
  float* A32 = (float*)(w + o);        o += (size_t)NEQ * NX * 4;     // 12.58 MB
  float* ADA = (float*)(w + o);        o += (size_t)768 * 768 * 4;    // 2.36 MB
  float* Ldiag = (float*)(w + o);      o += 12ull * 4096 * 4;         // 196 KB
  double* q    = (double*)(w + o);     o += NX * 8;
  double* ez   = (double*)(w + o);     o += NX * 8;
  double* z    = (double*)(w + o);     o += NX * 8;
  double* lam  = (double*)(w + o);     o += NX * 8;
  double* rtil = (double*)(w + o);     o += NX * 8;
  double* rc   = (double*)(w + o);     o += NX * 8;
  double* Di64 = (double*)(w + o);     o += NX * 8;
  double* dz   = (double*)(w + o);     o += NX * 8;
  double* dlam = (double*)(w + o);     o += NX * 8;
  double* atnu = (double*)(w + o);     o += 4ull * NX * 8;
  double* nu   = (double*)(w + o);     o += NEQ * 8;
  double* bv   = (double*)(w + o);     o += NEQ * 8;
  double* rp   = (double*)(w + o);     o += NEQ * 8;
  double* gap_slot = (double*)(w + o); o += 8;
  double* amin_part = (double*)(w + o);  o += 16 * 8;
  float* Di32  = (float*)(w + o);      o += NX * 4;
  float* w32   = (float*)(w + o);      o += NX * 4;
  float* atd_part = (float*)(w + o);   o += 4ull * NX * 4;
  float* rhs   = (float*)(w + o);      o += NEQ * 4;
  float* yv    = (float*)(w + o);      o += NEQ * 4;
  float* dnu32 = (float*)(w + o);      o += NEQ * 4;
  int*   dflag = (int*)(w + o);        o += 16;
  (void)ws_size; (void)in_sizes; (void)n_in; (void)out_size;   // ~15.8 MB used

  k_detect<<<1, 256, 0, stream>>>((const float*)Ap, dflag);
  k_convert<<<3072, 256, 0, stream>>>(Ap, dflag, A32);
  k_setup<<<17, 256, 0, stream>>>(puz, lz0p, dflag, q, ez, z, lam, nu);
  k_bvec<<<768, 256, 0, stream>>>(A32, ez, bv);

  for (int it = 0; it < NITER; ++it){
    k_resid<<<833, 256, 0, stream>>>(A32, nu, z, lam, bv, atnu, rp, gap_slot);
    k_elem<<<592, 256, 0, stream>>>(atnu, q, z, lam, gap_slot,
                                    rtil, rc, Di64, Di32, w32, ADA);
    k_ada<<<924, 256, 0, stream>>>(A32, Di32, w32, rp, ADA, rhs);
    for (int p = 0; p < 11; ++p){
      k_choltrsm<<<12 - p, 64, 0, stream>>>(ADA, rhs, Ldiag, yv, p);
      int nt = 11 - p;
      k_syrk<<<nt * (nt + 1) / 2, 256, 0, stream>>>(ADA, p);
    }
    k_cholback<<<1, 64, 0, stream>>>(ADA, rhs, Ldiag, yv, dnu32);
    k_atd<<<64, 256, 0, stream>>>(A32, dnu32, atd_part);
    k_step<<<16, 256, 0, stream>>>(rtil, rc, Di64, z, lam, atd_part, dz, dlam, amin_part);
    k_update<<<17, 256, 0, stream>>>(z, lam, nu, dz, dlam, dnu32, amin_part);
  }
  k_out<<<16, 256, 0, stream>>>(z, out);
}